// Round 9
// baseline (139.872 us; speedup 1.0000x reference)
//
#include <hip/hip_runtime.h>
#include <hip/hip_bf16.h>
#include <stdint.h>

// Problem constants (B, L, D, T) = (2, 2048, 1536, 2)
#define B_ 2
#define L_ 2048
#define D_ 1536

typedef __attribute__((ext_vector_type(4))) float  f32x4;
typedef __attribute__((ext_vector_type(8))) __bf16 bf16x8;

__device__ __forceinline__ unsigned short f2bf(float f) {
  unsigned int u = __float_as_uint(f);
  u += 0x7fffu + ((u >> 16) & 1u);   // RNE
  return (unsigned short)(u >> 16);
}

// ---------------------------------------------------------------------------
// Stage 1: hs(fp32) -> X(bf16), and P[t] = hs * Wp[t] (bf16), t in {0,1}
// ---------------------------------------------------------------------------
__global__ __launch_bounds__(256) void conv_kernel(
    const float* __restrict__ hs, const float* __restrict__ W,
    unsigned short* __restrict__ X, unsigned short* __restrict__ P) {
  const int idx  = blockIdx.x * 256 + threadIdx.x;
  const int base = idx * 4;
  const int d    = base % D_;
  const float4 h  = *(const float4*)(hs + base);
  const float4 w0 = *(const float4*)(W + d);
  const float4 w1 = *(const float4*)(W + 2 * D_ + d);
  ushort4 x, p0, p1;
  x.x  = f2bf(h.x);        x.y  = f2bf(h.y);        x.z  = f2bf(h.z);        x.w  = f2bf(h.w);
  p0.x = f2bf(h.x * w0.x); p0.y = f2bf(h.y * w0.y); p0.z = f2bf(h.z * w0.z); p0.w = f2bf(h.w * w0.w);
  p1.x = f2bf(h.x * w1.x); p1.y = f2bf(h.y * w1.y); p1.z = f2bf(h.z * w1.z); p1.w = f2bf(h.w * w1.w);
  *(ushort4*)(X + base) = x;
  *(ushort4*)(P + base) = p0;
  *(ushort4*)(P + (size_t)B_ * L_ * D_ + base) = p1;
}

// ---------------------------------------------------------------------------
// Stage 2: 256x256 tile, t fused along M. DRIFT-PIPELINED schedule, v2:
// 48 K-slices of BK=32; 4 LDS buffers x 32 KB; barrier every 2 phases.
// v2 change vs round 8 (53.3 us): both STG4s hoisted to WINDOW START
// (right after the boundary barrier) instead of mid-phase. Each staged
// slice is now issued a full window (~2000 cyc) before the vmcnt(0) that
// drains it -> boundary stall ~0, and phases are pure read+MFMA streams.
// WAR safe: stages target bufs {p+2,p+3}%4 whose previous readers were
// confirmed by the same barrier. Window w reads {2w,2w+1}, stages
// {2w+2,2w+3}; verified for all 24 windows (11x2 loop + 2 tail).
// Fragment geometry / swizzle / staging map / epilogue verbatim round-7/8
// (verified: 0 bank conflicts, absmax 0.0625).
// ---------------------------------------------------------------------------
__device__ __forceinline__ void gload16(const unsigned short* g, unsigned short* l) {
  __builtin_amdgcn_global_load_lds(
      (const __attribute__((address_space(1))) unsigned int*)g,
      (__attribute__((address_space(3))) unsigned int*)l, 16, 0, 0);
}

#define B0O 0
#define B1O 16384
#define B2O 32768
#define B3O 49152

__global__ __launch_bounds__(512, 2) void gemm_kernel(
    const unsigned short* __restrict__ X, const unsigned short* __restrict__ P,
    const float* __restrict__ bias, float2* __restrict__ out) {
  __shared__ unsigned short lds[65536];   // 128 KiB = 4 buffers x 16384 shorts

  const int tid = threadIdx.x;

  // ---- T1: XCD-aware bijective swizzle (256 % 8 == 0)
  const int id  = blockIdx.x;
  const int swz = (id & 7) * 32 + (id >> 3);
  const int bz  = swz >> 7;               // batch
  const int t2  = swz & 127;
  const int I0  = (t2 >> 3) * 128;        // 16 i-tiles
  const int J0  = (t2 & 7) * 256;         // 8 j-tiles

  const size_t planeB = (size_t)B_ * L_ * D_;

  // ---- staging: thread tid -> sub-block entry (row r = tid>>2, slot tid&3),
  // 16B each, LDS-linear. Source chunk inverse-swizzled:
  // c = (tid&3) ^ ((tid>>3)&3).
  const size_t gsrcOff = (size_t)(tid >> 2) * D_ +
                         (size_t)((((tid & 3) ^ ((tid >> 3) & 3))) * 8);
  const unsigned short* sA0 = P + (size_t)(bz * L_ + I0) * D_ + gsrcOff;   // P0
  const unsigned short* sA1 = sA0 + planeB;                                // P1
  const unsigned short* sB0 = X + (size_t)(bz * L_ + J0) * D_ + gsrcOff;   // X lo
  const unsigned short* sB1 = sB0 + (size_t)128 * D_;                      // X hi
  const int wuni = (tid >> 6) * 512;   // wave-uniform LDS base (shorts)

  // ---- compute geometry (16x16x32 frags; 8 waves = 2 wr x 4 wc)
  const int lane = tid & 63;
  const int w    = tid >> 6;
  const int wr   = w & 1;
  const int wc   = w >> 1;
  const int lr   = lane & 15;
  const int q    = lane >> 4;
  const int slot8 = ((q ^ ((lr >> 1) & 3)) * 8);   // read-side swizzled slot
  int aOff[8], bOff[4];
#pragma unroll
  for (int m = 0; m < 8; ++m)
    aOff[m] = (m >> 2) * 4096 + (wr * 64 + (m & 3) * 16 + lr) * 32;
#pragma unroll
  for (int n = 0; n < 4; ++n)
    bOff[n] = 8192 + (n >> 1) * 4096 + (wc * 32 + (n & 1) * 16 + lr) * 32;

  f32x4  acc[8][4] = {};
  bf16x8 aF[8], bF[4];

  // Buffer layout (shorts): buf + {A0:0, A1:4096, B0:8192, B1:12288};
  // each sub-block = 4096 shorts = 128 rows x 64 B.
#define STG4(NB, PN)                                                          \
  do {                                                                        \
    const size_t ko = (size_t)((PN) * 32);                                    \
    gload16(sA0 + ko, lds + (NB) + 0     + wuni);                             \
    gload16(sA1 + ko, lds + (NB) + 4096  + wuni);                             \
    gload16(sB0 + ko, lds + (NB) + 8192  + wuni);                             \
    gload16(sB1 + ko, lds + (NB) + 12288 + wuni);                             \
  } while (0)

#define RDALL(CB)                                                             \
  do {                                                                        \
    const unsigned short* base_ = lds + (CB) + slot8;                         \
    _Pragma("unroll") for (int m = 0; m < 8; ++m)                             \
      aF[m] = *(const bf16x8*)(base_ + aOff[m]);                              \
    _Pragma("unroll") for (int n = 0; n < 4; ++n)                             \
      bF[n] = *(const bf16x8*)(base_ + bOff[n]);                              \
  } while (0)

#define MMALL()                                                               \
  do {                                                                        \
    _Pragma("unroll") for (int m = 0; m < 8; ++m)                             \
      _Pragma("unroll") for (int n = 0; n < 4; ++n)                           \
        acc[m][n] = __builtin_amdgcn_mfma_f32_16x16x32_bf16(                  \
            aF[m], bF[n], acc[m][n], 0, 0, 0);                                \
  } while (0)

#define BNDRY()                                                               \
  do {                                                                        \
    asm volatile("s_waitcnt vmcnt(0)" ::: "memory");                          \
    __builtin_amdgcn_s_barrier();                                             \
    __builtin_amdgcn_sched_barrier(0);                                        \
  } while (0)

#define PRIO1() __builtin_amdgcn_s_setprio(1)
#define PRIO0() __builtin_amdgcn_s_setprio(0)

  // phase: read one slice's fragments from CB, run all 32 MFMAs.
  // No staging inside phases (hoisted to window start); no lgkmcnt(0)
  // drain (compiler inserts counted lgkmcnt per MFMA group).
#define PHR(CB)                                                               \
  do {                                                                        \
    RDALL(CB);                                                                \
    PRIO1(); MMALL(); PRIO0();                                                \
  } while (0)

  // ---- prologue: slices 0,1 into buffers 0,1
  STG4(B0O, 0);
  STG4(B1O, 1);

  // ---- main loop: 11 iters x 2 windows; windows 0..21, reads 0..43,
  // stages through slice 45.
#pragma unroll 1
  for (int it = 0; it < 11; ++it) {
    const int p0 = 4 * it;
    // even window: reads {p0,p0+1} (bufs 0,1); stages {p0+2,p0+3} (bufs 2,3)
    BNDRY();
    STG4(B2O, p0 + 2); STG4(B3O, p0 + 3);
    PHR(B0O); PHR(B1O);
    // odd window: reads {p0+2,p0+3} (bufs 2,3); stages {p0+4,p0+5} (bufs 0,1)
    BNDRY();
    STG4(B0O, p0 + 4); STG4(B1O, p0 + 5);
    PHR(B2O); PHR(B3O);
  }

  // ---- tail: window 22 reads {44,45}, stages {46,47}; window 23 reads {46,47}
  BNDRY();
  STG4(B2O, 46); STG4(B3O, 47);
  PHR(B0O); PHR(B1O);
  BNDRY();
  PHR(B2O); PHR(B3O);

#undef PHR
#undef BNDRY
#undef STG4
#undef RDALL
#undef MMALL

  // ---- epilogue (VERBATIM round-1/7/8): C/D col(j)=lane&15, row(i)=q*4+reg.
  // acc[m][.] (m<4) = t0, acc[m+4][.] = t1 at the SAME i -> dense float2.
  const float bias0 = bias[0], bias1 = bias[1];
#pragma unroll
  for (int m = 0; m < 4; ++m) {
#pragma unroll
    for (int r = 0; r < 4; ++r) {
      const int i = I0 + wr * 64 + m * 16 + q * 4 + r;
      float2* orow = out + (size_t)(bz * L_ + i) * L_;
#pragma unroll
      for (int n = 0; n < 4; ++n) {
        const int j = J0 + (n >> 1) * 128 + wc * 32 + (n & 1) * 16 + lr;
        float2 v;
        v.x = acc[m][n][r] + bias0;
        v.y = acc[m + 4][n][r] + bias1;
        orow[j] = v;
      }
    }
  }
}

extern "C" void kernel_launch(void* const* d_in, const int* in_sizes, int n_in,
                              void* d_out, int out_size, void* d_ws, size_t ws_size,
                              hipStream_t stream) {
  const float* hs   = (const float*)d_in[0];
  const float* W    = (const float*)d_in[1];
  const float* bias = (const float*)d_in[2];

  unsigned short* X = (unsigned short*)d_ws;                 // B*L*D bf16
  unsigned short* P = X + (size_t)B_ * L_ * D_;              // T*B*L*D bf16

  const int nconv = (B_ * L_ * D_ / 4) / 256;                // 6144 blocks
  conv_kernel<<<nconv, 256, 0, stream>>>(hs, W, X, P);

  gemm_kernel<<<256, 512, 0, stream>>>(X, P, bias, (float2*)d_out);
}

// Round 10
// 136.899 us; speedup vs baseline: 1.0217x; 1.0217x over previous
//
#include <hip/hip_runtime.h>
#include <hip/hip_bf16.h>
#include <stdint.h>

// Problem constants (B, L, D, T) = (2, 2048, 1536, 2)
#define B_ 2
#define L_ 2048
#define D_ 1536

typedef __attribute__((ext_vector_type(4))) float  f32x4;
typedef __attribute__((ext_vector_type(8))) __bf16 bf16x8;

__device__ __forceinline__ unsigned short f2bf(float f) {
  unsigned int u = __float_as_uint(f);
  u += 0x7fffu + ((u >> 16) & 1u);   // RNE
  return (unsigned short)(u >> 16);
}

// ---------------------------------------------------------------------------
// Stage 1: hs(fp32) -> X(bf16), and P[t] = hs * Wp[t] (bf16), t in {0,1}
// ---------------------------------------------------------------------------
__global__ __launch_bounds__(256) void conv_kernel(
    const float* __restrict__ hs, const float* __restrict__ W,
    unsigned short* __restrict__ X, unsigned short* __restrict__ P) {
  const int idx  = blockIdx.x * 256 + threadIdx.x;
  const int base = idx * 4;
  const int d    = base % D_;
  const float4 h  = *(const float4*)(hs + base);
  const float4 w0 = *(const float4*)(W + d);
  const float4 w1 = *(const float4*)(W + 2 * D_ + d);
  ushort4 x, p0, p1;
  x.x  = f2bf(h.x);        x.y  = f2bf(h.y);        x.z  = f2bf(h.z);        x.w  = f2bf(h.w);
  p0.x = f2bf(h.x * w0.x); p0.y = f2bf(h.y * w0.y); p0.z = f2bf(h.z * w0.z); p0.w = f2bf(h.w * w0.w);
  p1.x = f2bf(h.x * w1.x); p1.y = f2bf(h.y * w1.y); p1.z = f2bf(h.z * w1.z); p1.w = f2bf(h.w * w1.w);
  *(ushort4*)(X + base) = x;
  *(ushort4*)(P + base) = p0;
  *(ushort4*)(P + (size_t)B_ * L_ * D_ + base) = p1;
}

// ---------------------------------------------------------------------------
// Stage 2: 256x256 tile, t fused along M. DRIFT-PIPELINED schedule, v3:
// 48 K-slices of BK=32; 4 LDS buffers x 32 KB; ONE barrier per 2-phase
// window (round-8 structure, 53.3 us verified). v3 change vs round 8:
// BOTH window stages issued in phase A, AFTER phase A's RDALL (ds_reads
// keep the critical path; round-9 showed stage-before-RDALL costs 5.6 us)
// and BEFORE its MFMA cluster (gload issue burst hides under ds_read
// latency the wave waits out anyway). Youngest load now has ~1.5 phases
// (~1400 cyc) of slack at the boundary vmcnt(0) -> drain free; phase B is
// a pure read+MFMA stream. Sync/WAR identical to round 8 (stages target
// the buffer pair confirmed free by the same barrier).
// Fragment geometry / swizzle / staging map / epilogue verbatim round-7/8
// (verified: 0 bank conflicts, absmax 0.0625).
// ---------------------------------------------------------------------------
__device__ __forceinline__ void gload16(const unsigned short* g, unsigned short* l) {
  __builtin_amdgcn_global_load_lds(
      (const __attribute__((address_space(1))) unsigned int*)g,
      (__attribute__((address_space(3))) unsigned int*)l, 16, 0, 0);
}

#define B0O 0
#define B1O 16384
#define B2O 32768
#define B3O 49152

__global__ __launch_bounds__(512, 2) void gemm_kernel(
    const unsigned short* __restrict__ X, const unsigned short* __restrict__ P,
    const float* __restrict__ bias, float2* __restrict__ out) {
  __shared__ unsigned short lds[65536];   // 128 KiB = 4 buffers x 16384 shorts

  const int tid = threadIdx.x;

  // ---- T1: XCD-aware bijective swizzle (256 % 8 == 0)
  const int id  = blockIdx.x;
  const int swz = (id & 7) * 32 + (id >> 3);
  const int bz  = swz >> 7;               // batch
  const int t2  = swz & 127;
  const int I0  = (t2 >> 3) * 128;        // 16 i-tiles
  const int J0  = (t2 & 7) * 256;         // 8 j-tiles

  const size_t planeB = (size_t)B_ * L_ * D_;

  // ---- staging: thread tid -> sub-block entry (row r = tid>>2, slot tid&3),
  // 16B each, LDS-linear. Source chunk inverse-swizzled:
  // c = (tid&3) ^ ((tid>>3)&3).
  const size_t gsrcOff = (size_t)(tid >> 2) * D_ +
                         (size_t)((((tid & 3) ^ ((tid >> 3) & 3))) * 8);
  const unsigned short* sA0 = P + (size_t)(bz * L_ + I0) * D_ + gsrcOff;   // P0
  const unsigned short* sA1 = sA0 + planeB;                                // P1
  const unsigned short* sB0 = X + (size_t)(bz * L_ + J0) * D_ + gsrcOff;   // X lo
  const unsigned short* sB1 = sB0 + (size_t)128 * D_;                      // X hi
  const int wuni = (tid >> 6) * 512;   // wave-uniform LDS base (shorts)

  // ---- compute geometry (16x16x32 frags; 8 waves = 2 wr x 4 wc)
  const int lane = tid & 63;
  const int w    = tid >> 6;
  const int wr   = w & 1;
  const int wc   = w >> 1;
  const int lr   = lane & 15;
  const int q    = lane >> 4;
  const int slot8 = ((q ^ ((lr >> 1) & 3)) * 8);   // read-side swizzled slot
  int aOff[8], bOff[4];
#pragma unroll
  for (int m = 0; m < 8; ++m)
    aOff[m] = (m >> 2) * 4096 + (wr * 64 + (m & 3) * 16 + lr) * 32;
#pragma unroll
  for (int n = 0; n < 4; ++n)
    bOff[n] = 8192 + (n >> 1) * 4096 + (wc * 32 + (n & 1) * 16 + lr) * 32;

  f32x4  acc[8][4] = {};
  bf16x8 aF[8], bF[4];

  // Buffer layout (shorts): buf + {A0:0, A1:4096, B0:8192, B1:12288};
  // each sub-block = 4096 shorts = 128 rows x 64 B.
#define STG4(NB, PN)                                                          \
  do {                                                                        \
    const size_t ko = (size_t)((PN) * 32);                                    \
    gload16(sA0 + ko, lds + (NB) + 0     + wuni);                             \
    gload16(sA1 + ko, lds + (NB) + 4096  + wuni);                             \
    gload16(sB0 + ko, lds + (NB) + 8192  + wuni);                             \
    gload16(sB1 + ko, lds + (NB) + 12288 + wuni);                             \
  } while (0)

#define RDALL(CB)                                                             \
  do {                                                                        \
    const unsigned short* base_ = lds + (CB) + slot8;                         \
    _Pragma("unroll") for (int m = 0; m < 8; ++m)                             \
      aF[m] = *(const bf16x8*)(base_ + aOff[m]);                              \
    _Pragma("unroll") for (int n = 0; n < 4; ++n)                             \
      bF[n] = *(const bf16x8*)(base_ + bOff[n]);                              \
  } while (0)

#define MMALL()                                                               \
  do {                                                                        \
    _Pragma("unroll") for (int m = 0; m < 8; ++m)                             \
      _Pragma("unroll") for (int n = 0; n < 4; ++n)                           \
        acc[m][n] = __builtin_amdgcn_mfma_f32_16x16x32_bf16(                  \
            aF[m], bF[n], acc[m][n], 0, 0, 0);                                \
  } while (0)

#define BNDRY()                                                               \
  do {                                                                        \
    asm volatile("s_waitcnt vmcnt(0)" ::: "memory");                          \
    __builtin_amdgcn_s_barrier();                                             \
    __builtin_amdgcn_sched_barrier(0);                                        \
  } while (0)

#define PRIO1() __builtin_amdgcn_s_setprio(1)
#define PRIO0() __builtin_amdgcn_s_setprio(0)

  // phase A: ds_reads FIRST (critical path), then both window stages
  // (gload burst hides under ds_read latency), then MFMA cluster.
#define PHA(CB, SB1, PN1, SB2, PN2)                                           \
  do {                                                                        \
    RDALL(CB);                                                                \
    STG4(SB1, PN1); STG4(SB2, PN2);                                           \
    PRIO1(); MMALL(); PRIO0();                                                \
  } while (0)

  // phase B: pure read+MFMA stream.
#define PHB(CB)                                                               \
  do {                                                                        \
    RDALL(CB);                                                                \
    PRIO1(); MMALL(); PRIO0();                                                \
  } while (0)

  // ---- prologue: slices 0,1 into buffers 0,1
  STG4(B0O, 0);
  STG4(B1O, 1);

  // ---- main loop: 11 iters x 2 windows; reads 0..43, stages through 45.
#pragma unroll 1
  for (int it = 0; it < 11; ++it) {
    const int p0 = 4 * it;
    // even window: reads {p0,p0+1} (bufs 0,1); stages {p0+2,p0+3} (bufs 2,3)
    BNDRY();
    PHA(B0O, B2O, p0 + 2, B3O, p0 + 3);
    PHB(B1O);
    // odd window: reads {p0+2,p0+3} (bufs 2,3); stages {p0+4,p0+5} (bufs 0,1)
    BNDRY();
    PHA(B2O, B0O, p0 + 4, B1O, p0 + 5);
    PHB(B3O);
  }

  // ---- tail: window 22 reads {44,45}, stages {46,47}; window 23 reads {46,47}
  BNDRY();
  PHA(B0O, B2O, 46, B3O, 47);
  PHB(B1O);
  BNDRY();
  PHB(B2O);
  PHB(B3O);

#undef PHA
#undef PHB
#undef BNDRY
#undef STG4
#undef RDALL
#undef MMALL

  // ---- epilogue (VERBATIM round-1/7/8): C/D col(j)=lane&15, row(i)=q*4+reg.
  // acc[m][.] (m<4) = t0, acc[m+4][.] = t1 at the SAME i -> dense float2.
  const float bias0 = bias[0], bias1 = bias[1];
#pragma unroll
  for (int m = 0; m < 4; ++m) {
#pragma unroll
    for (int r = 0; r < 4; ++r) {
      const int i = I0 + wr * 64 + m * 16 + q * 4 + r;
      float2* orow = out + (size_t)(bz * L_ + i) * L_;
#pragma unroll
      for (int n = 0; n < 4; ++n) {
        const int j = J0 + (n >> 1) * 128 + wc * 32 + (n & 1) * 16 + lr;
        float2 v;
        v.x = acc[m][n][r] + bias0;
        v.y = acc[m + 4][n][r] + bias1;
        orow[j] = v;
      }
    }
  }
}

extern "C" void kernel_launch(void* const* d_in, const int* in_sizes, int n_in,
                              void* d_out, int out_size, void* d_ws, size_t ws_size,
                              hipStream_t stream) {
  const float* hs   = (const float*)d_in[0];
  const float* W    = (const float*)d_in[1];
  const float* bias = (const float*)d_in[2];

  unsigned short* X = (unsigned short*)d_ws;                 // B*L*D bf16
  unsigned short* P = X + (size_t)B_ * L_ * D_;              // T*B*L*D bf16

  const int nconv = (B_ * L_ * D_ / 4) / 256;                // 6144 blocks
  conv_kernel<<<nconv, 256, 0, stream>>>(hs, W, X, P);

  gemm_kernel<<<256, 512, 0, stream>>>(X, P, bias, (float2*)d_out);
}